// Round 4
// baseline (570.586 us; speedup 1.0000x reference)
//
#include <hip/hip_runtime.h>
#include <hip/hip_bf16.h>

typedef __bf16 bf16_t;
typedef __attribute__((ext_vector_type(8))) __bf16 bf16x8;
typedef __attribute__((ext_vector_type(4))) float f32x4;
typedef __attribute__((ext_vector_type(4))) float float4_t;

#define MFMA16(a, b, c) __builtin_amdgcn_mfma_f32_16x16x32_bf16((a), (b), (c), 0, 0, 0)

__device__ __forceinline__ float gelu_fast(float x) {
    // x * sigmoid(1.5958x + 0.07135x^3), exp base-2 folded
    float z = x * fmaf(x * x, -0.1029453f, -2.3022081f);
    float e = __builtin_amdgcn_exp2f(z);
    return x * __builtin_amdgcn_rcpf(1.0f + e);
}

__device__ __forceinline__ int lbound(const int* __restrict__ a, int n, int v) {
    int lo = 0, hi = n;
    while (lo < hi) { int mid = (lo + hi) >> 1; if (a[mid] < v) lo = mid + 1; else hi = mid; }
    return lo;
}

__device__ __forceinline__ int seg_of(const int* __restrict__ rsp, int lo, int hi, int er) {
    while (lo < hi) { int mid = (lo + hi + 1) >> 1; if (rsp[mid] <= er) lo = mid; else hi = mid - 1; }
    return lo;
}

__global__ __launch_bounds__(256, 3)
void nmlp_kernel(const float* __restrict__ in_f, const float* __restrict__ out_f,
                 const float* __restrict__ W1, const float* __restrict__ b1,
                 const float* __restrict__ W2, const float* __restrict__ b2,
                 const int* __restrict__ nbr, const int* __restrict__ rsp,
                 float* __restrict__ out, int M, int E, int epw, int nwaves)
{
    // LDS map: [0,16384) W1 frags bf16, [16384,32768) W2 frags (permuted rows),
    //          [32768,33280) b1 f32[128], [33280,33536) b2 f32[64]
    __shared__ alignas(16) unsigned char lds[33536];
    const int tid = threadIdx.x, lane = tid & 63, wslot = tid >> 6;
    const int g = lane >> 4, c = lane & 15;

    // ---- stage W1 into frag-major layout: frag(t,ks): W1[32ks+8g+j][16t+c], j contiguous ----
    for (int i = 0; i < 32; ++i) {
        int idx = i * 256 + tid;               // 0..8191
        int k = idx >> 7, n = idx & 127;
        int ks = k >> 5, gg = (k >> 3) & 3, j = k & 7, t = n >> 4, cc = n & 15;
        ((bf16_t*)lds)[(((2 * t + ks) * 4 + gg) * 16 + cc) * 8 + j] = (bf16_t)W1[idx];
    }
    // ---- stage W2, rows permuted so GEMM1 output renames directly into GEMM2 B-frags ----
    for (int i = 0; i < 32; ++i) {
        int idx = i * 256 + tid;               // 0..8191
        int l = idx >> 6, o = idx & 63;
        int t = l >> 4, gg = (l >> 2) & 3, j = l & 3;
        int k2 = t >> 1, j2 = (t & 1) * 4 + j, u = o >> 4, cc = o & 15;
        ((bf16_t*)lds)[8192 + (((u * 4 + k2) * 4 + gg) * 16 + cc) * 8 + j2] = (bf16_t)W2[idx];
    }
    if (tid < 128) *(float*)(lds + 32768 + tid * 4) = b1[tid];
    if (tid < 64)  *(float*)(lds + 33280 + tid * 4) = b2[tid];
    __syncthreads();

    const unsigned wbase = (unsigned)lane * 16u;

    const int wid = blockIdx.x * 4 + wslot;
    int sA = lbound(rsp, M + 1, wid * epw);
    int sB = lbound(rsp, M + 1, wid * epw + epw);
    if (sA > M) sA = M;
    if (sB > M) sB = M;
    if (wid == nwaves - 1) sB = M;             // cover trailing empty segments
    if (sA >= sB) return;

    int s = sA, e0c = rsp[s], e1c = rsp[s + 1];
    const int eS = e0c, eE = rsp[sB];

    f32x4 colacc[4];
    #pragma unroll
    for (int u = 0; u < 4; ++u) colacc[u] = (f32x4){0.f, 0.f, 0.f, 0.f};

    // masked accumulate of one 16-edge block + segment closes (all control wave-uniform)
    auto accum_close = [&](int bt, const f32x4* y) {
        const int tend = (bt + 16 < eE) ? bt + 16 : eE;
        const int er = bt + c;                 // this lane's edge id
        while (true) {
            int hi_p = (e1c < tend) ? e1c : tend;
            int lo_p = (e0c > bt) ? e0c : bt;
            float m = (er >= lo_p && er < hi_p) ? 1.0f : 0.0f;
            #pragma unroll
            for (int u = 0; u < 4; ++u)
                #pragma unroll
                for (int j = 0; j < 4; ++j)
                    colacc[u][j] = fmaf(y[u][j], m, colacc[u][j]);
            if (e1c <= tend) {
                const int d = e1c - e0c;
                const float inv = (d > 0) ? __builtin_amdgcn_rcpf((float)d) : 0.0f;
                float* orow = out + (size_t)s * 64;
                #pragma unroll
                for (int u = 0; u < 4; ++u) {
                    const f32x4 b2v = *(const f32x4*)(lds + 33280 + u * 64 + g * 16);
                    #pragma unroll
                    for (int j = 0; j < 4; ++j) {
                        float v = colacc[u][j];
                        v += __shfl_xor(v, 1); v += __shfl_xor(v, 2);
                        v += __shfl_xor(v, 4); v += __shfl_xor(v, 8);
                        if (c == 0) orow[u * 16 + g * 4 + j] = (d > 0) ? fmaf(v, inv, b2v[j]) : 0.0f;
                    }
                    colacc[u] = (f32x4){0.f, 0.f, 0.f, 0.f};
                }
                ++s; e0c = e1c;
                if (s >= sB) break;
                e1c = rsp[s + 1];
            } else break;
        }
    };

    if (eS < eE) {
        // prefetch blocks A (edges eS+c) and B (eS+16+c)
        int erA = eS + c;      if (erA > eE - 1) erA = eE - 1;
        int erB = eS + 16 + c; if (erB > eE - 1) erB = eE - 1;
        int nbA = nbr[erA], nbB = nbr[erB];
        int sgA = seg_of(rsp, s, sB - 1, erA), sgB = seg_of(rsp, s, sB - 1, erB);
        float4_t fA0, fA1, gA0, gA1, fB0, fB1, gB0, gB1;
        { const float4_t* p = (const float4_t*)(in_f  + (size_t)nbA * 32 + 8 * g); fA0 = p[0]; fA1 = p[1]; }
        { const float4_t* p = (const float4_t*)(out_f + (size_t)sgA * 32 + 8 * g); gA0 = p[0]; gA1 = p[1]; }
        { const float4_t* p = (const float4_t*)(in_f  + (size_t)nbB * 32 + 8 * g); fB0 = p[0]; fB1 = p[1]; }
        { const float4_t* p = (const float4_t*)(out_f + (size_t)sgB * 32 + 8 * g); gB0 = p[0]; gB1 = p[1]; }

        for (int et = eS; et < eE; et += 32) {
            // convert arrived features -> B-frags (lane supplies agg[edge c][8g+j])
            bf16x8 aA0, aA1, aB0, aB1;
            #pragma unroll
            for (int j = 0; j < 4; ++j) {
                aA0[j] = (bf16_t)fA0[j]; aA0[4 + j] = (bf16_t)fA1[j];
                aA1[j] = (bf16_t)gA0[j]; aA1[4 + j] = (bf16_t)gA1[j];
                aB0[j] = (bf16_t)fB0[j]; aB0[4 + j] = (bf16_t)fB1[j];
                aB1[j] = (bf16_t)gB0[j]; aB1[4 + j] = (bf16_t)gB1[j];
            }
            // kick next iteration's index loads + segment searches
            const bool more = (et + 32 < eE);
            int nbA2 = 0, sgA2 = 0, nbB2 = 0, sgB2 = 0;
            if (more) {
                int eA2 = et + 32 + c; if (eA2 > eE - 1) eA2 = eE - 1;
                int eB2 = et + 48 + c; if (eB2 > eE - 1) eB2 = eE - 1;
                nbA2 = nbr[eA2]; nbB2 = nbr[eB2];
                sgA2 = seg_of(rsp, s, sB - 1, eA2); sgB2 = seg_of(rsp, s, sB - 1, eB2);
            }
            // ---- GEMM1': h^T = W1^T(LDS frags) x agg^T(regs); GELU; pack to GEMM2 B-frags ----
            bf16x8 phA[4], phB[4];
            #pragma unroll
            for (int t = 0; t < 8; ++t) {
                const f32x4 b1v  = *(const f32x4*)(lds + 32768 + t * 64 + g * 16);
                const bf16x8 w10 = *(const bf16x8*)(lds + wbase + (2 * t) * 1024);
                const bf16x8 w11 = *(const bf16x8*)(lds + wbase + (2 * t + 1) * 1024);
                f32x4 hA = b1v, hB = b1v;
                hA = MFMA16(w10, aA0, hA); hA = MFMA16(w11, aA1, hA);
                hB = MFMA16(w10, aB0, hB); hB = MFMA16(w11, aB1, hB);
                #pragma unroll
                for (int j = 0; j < 4; ++j) {
                    phA[t >> 1][(t & 1) * 4 + j] = (bf16_t)gelu_fast(hA[j]);
                    phB[t >> 1][(t & 1) * 4 + j] = (bf16_t)gelu_fast(hB[j]);
                }
            }
            // issue next iteration's feature-row loads (hide under GEMM2)
            if (more) {
                { const float4_t* p = (const float4_t*)(in_f  + (size_t)nbA2 * 32 + 8 * g); fA0 = p[0]; fA1 = p[1]; }
                { const float4_t* p = (const float4_t*)(out_f + (size_t)sgA2 * 32 + 8 * g); gA0 = p[0]; gA1 = p[1]; }
                { const float4_t* p = (const float4_t*)(in_f  + (size_t)nbB2 * 32 + 8 * g); fB0 = p[0]; fB1 = p[1]; }
                { const float4_t* p = (const float4_t*)(out_f + (size_t)sgB2 * 32 + 8 * g); gB0 = p[0]; gB1 = p[1]; }
            }
            // ---- GEMM2': y^T = W2^T(perm LDS frags) x h^T(regs), weight reads shared A/B ----
            f32x4 yA[4], yB[4];
            #pragma unroll
            for (int u = 0; u < 4; ++u) { yA[u] = (f32x4){0.f,0.f,0.f,0.f}; yB[u] = (f32x4){0.f,0.f,0.f,0.f}; }
            #pragma unroll
            for (int u = 0; u < 4; ++u)
                #pragma unroll
                for (int k2 = 0; k2 < 4; ++k2) {
                    const bf16x8 w2 = *(const bf16x8*)(lds + 16384 + wbase + (u * 4 + k2) * 1024);
                    yA[u] = MFMA16(w2, phA[k2], yA[u]);
                    yB[u] = MFMA16(w2, phB[k2], yB[u]);
                }
            accum_close(et, yA);
            if (et + 16 < eE) accum_close(et + 16, yB);
        }
    }
    // all-empty range tail
    while (s < sB) {
        float* orow = out + (size_t)s * 64;
        if (c == 0) {
            #pragma unroll
            for (int u = 0; u < 4; ++u)
                #pragma unroll
                for (int j = 0; j < 4; ++j) orow[u * 16 + g * 4 + j] = 0.0f;
        }
        ++s;
    }
}

extern "C" void kernel_launch(void* const* d_in, const int* in_sizes, int n_in,
                              void* d_out, int out_size, void* d_ws, size_t ws_size,
                              hipStream_t stream) {
    const float* in_f  = (const float*)d_in[0];
    const float* out_f = (const float*)d_in[1];
    const float* W1    = (const float*)d_in[2];
    const float* b1    = (const float*)d_in[3];
    const float* W2    = (const float*)d_in[4];
    const float* b2    = (const float*)d_in[5];
    const int*   nbr   = (const int*)d_in[6];
    const int*   rsp   = (const int*)d_in[7];
    float* out = (float*)d_out;
    const int M = in_sizes[7] - 1;
    const int E = in_sizes[6];

    const int nblocks = 768;              // 3 blocks/CU resident at 3 waves/SIMD target
    const int nwaves  = nblocks * 4;
    const int epw = (E + nwaves - 1) / nwaves;

    nmlp_kernel<<<dim3(nblocks), dim3(256), 0, stream>>>(in_f, out_f, W1, b1, W2, b2,
                                                         nbr, rsp, out, M, E, epw, nwaves);
}

// Round 5
// 297.114 us; speedup vs baseline: 1.9204x; 1.9204x over previous
//
#include <hip/hip_runtime.h>
#include <hip/hip_bf16.h>

typedef __bf16 bf16_t;
typedef __attribute__((ext_vector_type(8))) __bf16 bf16x8;
typedef __attribute__((ext_vector_type(4))) float f32x4;
typedef __attribute__((ext_vector_type(4))) float float4_t;

#define MFMA16(a, b, c) __builtin_amdgcn_mfma_f32_16x16x32_bf16((a), (b), (c), 0, 0, 0)

__device__ __forceinline__ float gelu_fast(float x) {
    // x * sigmoid(1.5958x + 0.07135x^3), exp base-2 folded
    float z = x * fmaf(x * x, -0.1029453f, -2.3022081f);
    float e = __builtin_amdgcn_exp2f(z);
    return x * __builtin_amdgcn_rcpf(1.0f + e);
}

__device__ __forceinline__ int lbound(const int* __restrict__ a, int n, int v) {
    int lo = 0, hi = n;
    while (lo < hi) { int mid = (lo + hi) >> 1; if (a[mid] < v) lo = mid + 1; else hi = mid; }
    return lo;
}

__device__ __forceinline__ int seg_of(const int* __restrict__ rsp, int lo, int hi, int er) {
    while (lo < hi) { int mid = (lo + hi + 1) >> 1; if (rsp[mid] <= er) lo = mid; else hi = mid - 1; }
    return lo;
}

__global__ __launch_bounds__(256, 2)
void nmlp_kernel(const float* __restrict__ in_f, const float* __restrict__ out_f,
                 const float* __restrict__ W1, const float* __restrict__ b1,
                 const float* __restrict__ W2, const float* __restrict__ b2,
                 const int* __restrict__ nbr, const int* __restrict__ rsp,
                 float* __restrict__ out, int M, int E, int epw, int nwaves)
{
    // LDS map: [0,16384) W1 frags bf16, [16384,32768) W2 frags (permuted rows),
    //          [32768,33280) b1 f32[128], [33280,33536) b2 f32[64]
    __shared__ alignas(16) unsigned char lds[33536];
    const int tid = threadIdx.x, lane = tid & 63, wslot = tid >> 6;
    const int g = lane >> 4, c = lane & 15;

    // ---- stage W1 into frag-major layout: frag(t,ks): W1[32ks+8g+j][16t+c], j contiguous ----
    for (int i = 0; i < 32; ++i) {
        int idx = i * 256 + tid;               // 0..8191
        int k = idx >> 7, n = idx & 127;
        int ks = k >> 5, gg = (k >> 3) & 3, j = k & 7, t = n >> 4, cc = n & 15;
        ((bf16_t*)lds)[(((2 * t + ks) * 4 + gg) * 16 + cc) * 8 + j] = (bf16_t)W1[idx];
    }
    // ---- stage W2, rows permuted so GEMM1 output renames directly into GEMM2 B-frags ----
    for (int i = 0; i < 32; ++i) {
        int idx = i * 256 + tid;               // 0..8191
        int l = idx >> 6, o = idx & 63;
        int t = l >> 4, gg = (l >> 2) & 3, j = l & 3;
        int k2 = t >> 1, j2 = (t & 1) * 4 + j, u = o >> 4, cc = o & 15;
        ((bf16_t*)lds)[8192 + (((u * 4 + k2) * 4 + gg) * 16 + cc) * 8 + j2] = (bf16_t)W2[idx];
    }
    if (tid < 128) *(float*)(lds + 32768 + tid * 4) = b1[tid];
    if (tid < 64)  *(float*)(lds + 33280 + tid * 4) = b2[tid];
    __syncthreads();

    const unsigned wbase = (unsigned)lane * 16u;

    const int wid = blockIdx.x * 4 + wslot;
    int sA = lbound(rsp, M + 1, wid * epw);
    int sB = lbound(rsp, M + 1, wid * epw + epw);
    if (sA > M) sA = M;
    if (sB > M) sB = M;
    if (wid == nwaves - 1) sB = M;             // cover trailing empty segments
    if (sA >= sB) return;

    int s = sA, e0c = rsp[s], e1c = rsp[s + 1];
    const int eS = e0c, eE = rsp[sB];

    f32x4 colacc[4];
    #pragma unroll
    for (int u = 0; u < 4; ++u) colacc[u] = (f32x4){0.f, 0.f, 0.f, 0.f};

    // masked accumulate of one 16-edge block + segment closes (all control wave-uniform)
    auto accum_close = [&](int bt, const f32x4* y) {
        const int tend = (bt + 16 < eE) ? bt + 16 : eE;
        const int er = bt + c;                 // this lane's edge id
        while (true) {
            int hi_p = (e1c < tend) ? e1c : tend;
            int lo_p = (e0c > bt) ? e0c : bt;
            float m = (er >= lo_p && er < hi_p) ? 1.0f : 0.0f;
            #pragma unroll
            for (int u = 0; u < 4; ++u)
                #pragma unroll
                for (int j = 0; j < 4; ++j)
                    colacc[u][j] = fmaf(y[u][j], m, colacc[u][j]);
            if (e1c <= tend) {
                const int d = e1c - e0c;
                const float inv = (d > 0) ? __builtin_amdgcn_rcpf((float)d) : 0.0f;
                float* orow = out + (size_t)s * 64;
                #pragma unroll
                for (int u = 0; u < 4; ++u) {
                    const f32x4 b2v = *(const f32x4*)(lds + 33280 + u * 64 + g * 16);
                    #pragma unroll
                    for (int j = 0; j < 4; ++j) {
                        float v = colacc[u][j];
                        v += __shfl_xor(v, 1); v += __shfl_xor(v, 2);
                        v += __shfl_xor(v, 4); v += __shfl_xor(v, 8);
                        if (c == 0) orow[u * 16 + g * 4 + j] = (d > 0) ? fmaf(v, inv, b2v[j]) : 0.0f;
                    }
                    colacc[u] = (f32x4){0.f, 0.f, 0.f, 0.f};
                }
                ++s; e0c = e1c;
                if (s >= sB) break;
                e1c = rsp[s + 1];
            } else break;
        }
    };

    if (eS < eE) {
        // prefetch blocks A (edges eS+c) and B (eS+16+c)
        int erA = eS + c;      if (erA > eE - 1) erA = eE - 1;
        int erB = eS + 16 + c; if (erB > eE - 1) erB = eE - 1;
        int nbA = nbr[erA], nbB = nbr[erB];
        int sgA = seg_of(rsp, s, sB - 1, erA), sgB = seg_of(rsp, s, sB - 1, erB);
        float4_t fA0, fA1, gA0, gA1, fB0, fB1, gB0, gB1;
        { const float4_t* p = (const float4_t*)(in_f  + (size_t)nbA * 32 + 8 * g); fA0 = p[0]; fA1 = p[1]; }
        { const float4_t* p = (const float4_t*)(out_f + (size_t)sgA * 32 + 8 * g); gA0 = p[0]; gA1 = p[1]; }
        { const float4_t* p = (const float4_t*)(in_f  + (size_t)nbB * 32 + 8 * g); fB0 = p[0]; fB1 = p[1]; }
        { const float4_t* p = (const float4_t*)(out_f + (size_t)sgB * 32 + 8 * g); gB0 = p[0]; gB1 = p[1]; }

        for (int et = eS; et < eE; et += 32) {
            // convert arrived features -> B-frags (lane supplies agg[edge c][8g+j])
            bf16x8 aA0, aA1, aB0, aB1;
            #pragma unroll
            for (int j = 0; j < 4; ++j) {
                aA0[j] = (bf16_t)fA0[j]; aA0[4 + j] = (bf16_t)fA1[j];
                aA1[j] = (bf16_t)gA0[j]; aA1[4 + j] = (bf16_t)gA1[j];
                aB0[j] = (bf16_t)fB0[j]; aB0[4 + j] = (bf16_t)fB1[j];
                aB1[j] = (bf16_t)gB0[j]; aB1[4 + j] = (bf16_t)gB1[j];
            }
            // kick next iteration's index loads + segment searches
            const bool more = (et + 32 < eE);
            int nbA2 = 0, sgA2 = 0, nbB2 = 0, sgB2 = 0;
            if (more) {
                int eA2 = et + 32 + c; if (eA2 > eE - 1) eA2 = eE - 1;
                int eB2 = et + 48 + c; if (eB2 > eE - 1) eB2 = eE - 1;
                nbA2 = nbr[eA2]; nbB2 = nbr[eB2];
                sgA2 = seg_of(rsp, s, sB - 1, eA2); sgB2 = seg_of(rsp, s, sB - 1, eB2);
            }
            // ---- GEMM1': h^T = W1^T(LDS frags) x agg^T(regs); GELU; pack to GEMM2 B-frags ----
            bf16x8 phA[4], phB[4];
            #pragma unroll
            for (int t = 0; t < 8; ++t) {
                const f32x4 b1v  = *(const f32x4*)(lds + 32768 + t * 64 + g * 16);
                const bf16x8 w10 = *(const bf16x8*)(lds + wbase + (2 * t) * 1024);
                const bf16x8 w11 = *(const bf16x8*)(lds + wbase + (2 * t + 1) * 1024);
                f32x4 hA = b1v, hB = b1v;
                hA = MFMA16(w10, aA0, hA); hA = MFMA16(w11, aA1, hA);
                hB = MFMA16(w10, aB0, hB); hB = MFMA16(w11, aB1, hB);
                #pragma unroll
                for (int j = 0; j < 4; ++j) {
                    phA[t >> 1][(t & 1) * 4 + j] = (bf16_t)gelu_fast(hA[j]);
                    phB[t >> 1][(t & 1) * 4 + j] = (bf16_t)gelu_fast(hB[j]);
                }
            }
            // issue next iteration's feature-row loads (hide under GEMM2)
            if (more) {
                { const float4_t* p = (const float4_t*)(in_f  + (size_t)nbA2 * 32 + 8 * g); fA0 = p[0]; fA1 = p[1]; }
                { const float4_t* p = (const float4_t*)(out_f + (size_t)sgA2 * 32 + 8 * g); gA0 = p[0]; gA1 = p[1]; }
                { const float4_t* p = (const float4_t*)(in_f  + (size_t)nbB2 * 32 + 8 * g); fB0 = p[0]; fB1 = p[1]; }
                { const float4_t* p = (const float4_t*)(out_f + (size_t)sgB2 * 32 + 8 * g); gB0 = p[0]; gB1 = p[1]; }
            }
            // ---- GEMM2': y^T = W2^T(perm LDS frags) x h^T(regs), weight reads shared A/B ----
            f32x4 yA[4], yB[4];
            #pragma unroll
            for (int u = 0; u < 4; ++u) { yA[u] = (f32x4){0.f,0.f,0.f,0.f}; yB[u] = (f32x4){0.f,0.f,0.f,0.f}; }
            #pragma unroll
            for (int u = 0; u < 4; ++u)
                #pragma unroll
                for (int k2 = 0; k2 < 4; ++k2) {
                    const bf16x8 w2 = *(const bf16x8*)(lds + 16384 + wbase + (u * 4 + k2) * 1024);
                    yA[u] = MFMA16(w2, phA[k2], yA[u]);
                    yB[u] = MFMA16(w2, phB[k2], yB[u]);
                }
            accum_close(et, yA);
            if (et + 16 < eE) accum_close(et + 16, yB);
        }
    }
    // all-empty range tail
    while (s < sB) {
        float* orow = out + (size_t)s * 64;
        if (c == 0) {
            #pragma unroll
            for (int u = 0; u < 4; ++u)
                #pragma unroll
                for (int j = 0; j < 4; ++j) orow[u * 16 + g * 4 + j] = 0.0f;
        }
        ++s;
    }
}

extern "C" void kernel_launch(void* const* d_in, const int* in_sizes, int n_in,
                              void* d_out, int out_size, void* d_ws, size_t ws_size,
                              hipStream_t stream) {
    const float* in_f  = (const float*)d_in[0];
    const float* out_f = (const float*)d_in[1];
    const float* W1    = (const float*)d_in[2];
    const float* b1    = (const float*)d_in[3];
    const float* W2    = (const float*)d_in[4];
    const float* b2    = (const float*)d_in[5];
    const int*   nbr   = (const int*)d_in[6];
    const int*   rsp   = (const int*)d_in[7];
    float* out = (float*)d_out;
    const int M = in_sizes[7] - 1;
    const int E = in_sizes[6];

    const int nblocks = 512;              // 2 blocks/CU resident at 2 waves/SIMD (no alloc force past fit)
    const int nwaves  = nblocks * 4;
    const int epw = (E + nwaves - 1) / nwaves;

    nmlp_kernel<<<dim3(nblocks), dim3(256), 0, stream>>>(in_f, out_f, W1, b1, W2, b2,
                                                         nbr, rsp, out, M, E, epw, nwaves);
}